// Round 5
// baseline (968.756 us; speedup 1.0000x reference)
//
#include <hip/hip_runtime.h>

#define S_TOK 8192
#define DIM   1024
#define DIM2  2048
#define OUTN  1024

typedef __bf16 bf16x8 __attribute__((ext_vector_type(8)));
typedef float  f32x4  __attribute__((ext_vector_type(4)));
typedef short  s16x8  __attribute__((ext_vector_type(8)));
typedef unsigned short u16x4 __attribute__((ext_vector_type(4)));

__device__ __forceinline__ unsigned short f2bf(float x) {
  unsigned u = __builtin_bit_cast(unsigned, x);
  u = (u + 0x7FFFu + ((u >> 16) & 1u)) >> 16;
  return (unsigned short)u;
}
__device__ __forceinline__ float bf2f(unsigned short u) {
  return __builtin_bit_cast(float, (unsigned)u << 16);
}

__device__ __forceinline__ void gld_lds16(const void* g, void* l) {
  auto* g1 = reinterpret_cast<__attribute__((address_space(1))) unsigned*>(
      (unsigned long long)g);
  auto* l3 = reinterpret_cast<__attribute__((address_space(3))) unsigned*>(
      (unsigned long long)l);
  __builtin_amdgcn_global_load_lds(g1, l3, 16, 0, 0);
}

// m201 st_16x32 swizzle for a [rows][64] bf16 tile (row stride 128B):
// byte ^= ((byte>>9)&1)<<5, i.e. XOR byte-bit5 (32B granule) with row-bit2.
// HW-verified conflict-free for the b128 fragment-read pattern used below.
// Staging keeps the LDS write LINEAR and pre-XORs the GLOBAL source k-chunk
// (involution => same XOR on both sides).
__device__ __forceinline__ int lds_off(int idx, int k) {
  return ((idx << 7) + (k << 1)) ^ (((idx >> 2) & 1) << 5);
}

__global__ __launch_bounds__(256) void cvt_f32_bf16(const float* __restrict__ in,
                                                    unsigned short* __restrict__ out, int n4) {
  int i = blockIdx.x * 256 + threadIdx.x;
  if (i >= n4) return;
  float4 v = ((const float4*)in)[i];
  u16x4 o;
  o[0] = f2bf(v.x); o[1] = f2bf(v.y); o[2] = f2bf(v.z); o[3] = f2bf(v.w);
  *(u16x4*)(out + (size_t)i * 4) = o;
}

// Tiled transpose: in [R,C] (f32 or bf16) -> out [C,R] bf16. 64x64 tiles, 256 thr.
template <int F32IN>
__global__ __launch_bounds__(256) void transpose_to_bf16(const void* __restrict__ in,
                                                         unsigned short* __restrict__ out,
                                                         int R, int C) {
  __shared__ unsigned short t[64 * 64];
  const int r0 = blockIdx.y << 6, c0 = blockIdx.x << 6;
  const int tid = threadIdx.x;
#pragma unroll
  for (int i = 0; i < 2; ++i) {
    int ch = tid + (i << 8);
    int r = ch >> 3, c8 = (ch & 7) << 3;
    s16x8 w;
    if (F32IN) {
      const float* p = (const float*)in + (size_t)(r0 + r) * C + c0 + c8;
      float4 a = *(const float4*)p, b = *(const float4*)(p + 4);
      w[0] = (short)f2bf(a.x); w[1] = (short)f2bf(a.y);
      w[2] = (short)f2bf(a.z); w[3] = (short)f2bf(a.w);
      w[4] = (short)f2bf(b.x); w[5] = (short)f2bf(b.y);
      w[6] = (short)f2bf(b.z); w[7] = (short)f2bf(b.w);
    } else {
      w = *(const s16x8*)((const unsigned short*)in + (size_t)(r0 + r) * C + c0 + c8);
    }
    int sw = ((r ^ (r >> 3)) & 7) << 3;
    *(s16x8*)&t[(r << 6) + (c8 ^ sw)] = w;
  }
  __syncthreads();
#pragma unroll
  for (int i = 0; i < 2; ++i) {
    int ch = tid + (i << 8);
    int c = ch >> 3, r8 = (ch & 7) << 3;
    s16x8 w;
#pragma unroll
    for (int j = 0; j < 8; ++j) {
      int rr = r8 + j;
      w[j] = (short)t[(rr << 6) + (c ^ (((rr ^ (rr >> 3)) & 7) << 3))];
    }
    *(s16x8*)(out + (size_t)(c0 + c) * R + r0 + r8) = w;
  }
}

// Softmax over the ROW axis (2048 feats) of T [2048, S_TOK], per column, in place.
struct SmTab { unsigned short* T[6]; };
__global__ __launch_bounds__(512) void softmax_cols(SmTab tab) {
  unsigned short* T = tab.T[blockIdx.y];
  const int tid = threadIdx.x;
  const int colg = tid & 63, seg = tid >> 6;
  const size_t c = ((size_t)blockIdx.x << 6) + colg;
  float m = -1e30f, s = 0.f;
  for (int n = seg; n < DIM2; n += 8) {
    float v = bf2f(T[(size_t)n * S_TOK + c]);
    float mn = fmaxf(m, v);
    s = s * __expf(m - mn) + __expf(v - mn);
    m = mn;
  }
  __shared__ float redm[512], reds[512];
  redm[tid] = m; reds[tid] = s;
  __syncthreads();
  if (seg == 0) {
    float M = m, S = s;
#pragma unroll
    for (int k = 1; k < 8; ++k) {
      float mk = redm[colg + (k << 6)], sk = reds[colg + (k << 6)];
      float mn = fmaxf(M, mk);
      S = S * __expf(M - mn) + sk * __expf(mk - mn);
      M = mn;
    }
    redm[colg] = M; reds[colg] = 1.0f / S;
  }
  __syncthreads();
  m = redm[colg];
  const float inv = reds[colg];
  for (int n = seg; n < DIM2; n += 8) {
    size_t idx = (size_t)n * S_TOK + c;
    T[idx] = f2bf(__expf(bf2f(T[idx]) - m) * inv);
  }
}

struct GPtr {
  const unsigned short* A[3];
  const unsigned short* Arow2[3];
  const unsigned short* B[3];
  const unsigned short* Bk2[3];
  const float* bias[3];
  void* C[3];
};

// ---------------- 128x128 kernel (small GEMMs: G4, G5) ----------------
template <int ASPLIT, int BSPLIT, int BIAS_ROW, int OUT_BF16>
__global__ __launch_bounds__(256, 3) void gemm_nt(GPtr p, int lda, int ldb, int ldc,
                                                  int K, float scale, int do_relu) {
  __shared__ char lds[32768];
  char* As = lds;
  char* Bs = lds + 16384;
  const int z = blockIdx.z;
  const int tid  = threadIdx.x;
  const int lane = tid & 63;
  const int wave = tid >> 6;
  const int wm = (wave >> 1) << 6;
  const int wn = (wave & 1) << 6;
  const int m0 = blockIdx.y << 7;
  const int n0 = blockIdx.x << 7;

  const unsigned short* Au = p.A[z];
  int mb = m0;
  if (ASPLIT && m0 >= 2048) { Au = p.Arow2[z]; mb = m0 - 2048; }
  const unsigned short* B  = p.B[z];
  const unsigned short* B2 = BSPLIT ? p.Bk2[z] : B;
  const float* bias = p.bias[z];
  void* Cv = p.C[z];

  int srow[4], sgk[4];
#pragma unroll
  for (int i = 0; i < 4; ++i) {
    int c = (wave << 8) + (i << 6) + lane;
    int row = c >> 3, kc = c & 7;
    srow[i] = row;
    sgk[i]  = (kc ^ (((row >> 2) & 1) << 1)) << 3;  // st_16x32 pre-swizzle
  }

  f32x4 acc[4][4];
#pragma unroll
  for (int i = 0; i < 4; ++i)
#pragma unroll
    for (int j = 0; j < 4; ++j) acc[i][j] = {0.f, 0.f, 0.f, 0.f};

  for (int k0 = 0; k0 < K; k0 += 64) {
    const unsigned short* bsrc = B;
    int kb = k0;
    if (BSPLIT && k0 >= DIM) { bsrc = B2; kb = k0 - DIM; }
#pragma unroll
    for (int i = 0; i < 4; ++i) {
      char* dA = As + (((wave << 2) + i) << 10);
      char* dB = Bs + (((wave << 2) + i) << 10);
      gld_lds16(Au   + (size_t)(mb + srow[i]) * lda + k0 + sgk[i], dA);
      gld_lds16(bsrc + (size_t)(n0 + srow[i]) * ldb + kb + sgk[i], dB);
    }
    __syncthreads();
#pragma unroll
    for (int ks = 0; ks < 2; ++ks) {
      bf16x8 af[4], bfr[4];
      int kk = (ks << 5) + ((lane >> 4) << 3);
#pragma unroll
      for (int t = 0; t < 4; ++t) {
        af[t]  = *(const bf16x8*)(As + lds_off(wm + (t << 4) + (lane & 15), kk));
        bfr[t] = *(const bf16x8*)(Bs + lds_off(wn + (t << 4) + (lane & 15), kk));
      }
#pragma unroll
      for (int mt = 0; mt < 4; ++mt)
#pragma unroll
        for (int nt = 0; nt < 4; ++nt)
          acc[mt][nt] = __builtin_amdgcn_mfma_f32_16x16x32_bf16(af[mt], bfr[nt], acc[mt][nt], 0, 0, 0);
    }
    __syncthreads();
  }

#pragma unroll
  for (int nt = 0; nt < 4; ++nt) {
    int col = n0 + wn + (nt << 4) + (lane & 15);
    float bcol = (!BIAS_ROW && bias) ? bias[col] : 0.0f;
#pragma unroll
    for (int mt = 0; mt < 4; ++mt) {
      f32x4 a = acc[mt][nt];
#pragma unroll
      for (int r = 0; r < 4; ++r) {
        int rowg = m0 + wm + (mt << 4) + ((lane >> 4) << 2) + r;
        float bv = BIAS_ROW ? (bias ? bias[rowg] : 0.0f) : bcol;
        float v = a[r] * scale + bv;
        if (do_relu) v = fmaxf(v, 0.0f);
        if (OUT_BF16) ((unsigned short*)Cv)[(size_t)rowg * ldc + col] = f2bf(v);
        else          ((float*)Cv)[(size_t)rowg * ldc + col] = v;
      }
    }
  }
}

// ---------------- 256x256 counted-vmcnt pipelined kernel ----------------
// BM=BN=256, BK=64, 512 thr = 8 waves (2M x 4N), per-wave 128x64 output.
// LDS 128KB double-buffered; 2-deep prefetch with counted s_waitcnt vmcnt(8)
// across raw s_barrier; phase-split MFMA clusters with setprio.
template <int ASPLIT, int BSPLIT, int BIAS_ROW, int OUT_BF16>
__global__ __launch_bounds__(512, 2) void gemm256(GPtr p, int lda, int ldb, int ldc,
                                                  int K, float scale, int do_relu) {
  __shared__ char lds[131072];
  const int z = blockIdx.z;
  const int tid  = threadIdx.x;
  const int lane = tid & 63;
  const int wave = tid >> 6;      // 0..7
  const int wm   = wave >> 2;     // 0..1  (M half)
  const int wn   = wave & 3;      // 0..3  (N quarter)

  // bijective XCD-chunked swizzle of the (x,y) block id (nwg % 8 == 0)
  const int gx = gridDim.x;
  const int nwg = gx * gridDim.y;
  int id = blockIdx.y * gx + blockIdx.x;
  id = (id & 7) * (nwg >> 3) + (id >> 3);
  const int n0 = (id % gx) << 8;
  const int m0 = (id / gx) << 8;

  const unsigned short* Au = p.A[z];
  int mb = m0;
  if (ASPLIT && m0 >= 2048) { Au = p.Arow2[z]; mb = m0 - 2048; }
  const unsigned short* Bp = p.B[z];
  const unsigned short* B2 = BSPLIT ? p.Bk2[z] : Bp;
  const float* bias = p.bias[z];
  void* Cv = p.C[z];

  // staging: A tile 256x64 = 2048 16B-chunks; chunk c = i*512 + tid.
  int srow[4], sgk[4];
#pragma unroll
  for (int i = 0; i < 4; ++i) {
    int c = (i << 9) + tid;
    int row = c >> 3, kc = c & 7;
    srow[i] = row;
    sgk[i]  = (kc ^ (((row >> 2) & 1) << 1)) << 3;  // st_16x32 pre-swizzle
  }

  auto stage = [&](int t) {
    const int k0 = t << 6;
    char* Abase = lds + ((t & 1) << 16);
    char* Bbase = Abase + 32768;
    const unsigned short* bsrc = Bp;
    int kb = k0;
    if (BSPLIT && k0 >= DIM) { bsrc = B2; kb = k0 - DIM; }
#pragma unroll
    for (int i = 0; i < 4; ++i) {
      gld_lds16(Au   + (size_t)(mb + srow[i]) * lda + k0 + sgk[i],
                Abase + (i << 13) + (wave << 10));
      gld_lds16(bsrc + (size_t)(n0 + srow[i]) * ldb + kb + sgk[i],
                Bbase + (i << 13) + (wave << 10));
    }
  };

  f32x4 acc[8][4];
#pragma unroll
  for (int i = 0; i < 8; ++i)
#pragma unroll
    for (int j = 0; j < 4; ++j) acc[i][j] = {0.f, 0.f, 0.f, 0.f};

  const int NT = K >> 6;  // >= 2, even
  stage(0);
  stage(1);

  for (int t = 0; t < NT; ++t) {
    if (t + 1 < NT) asm volatile("s_waitcnt vmcnt(8)" ::: "memory");
    else            asm volatile("s_waitcnt vmcnt(0)" ::: "memory");
    __builtin_amdgcn_s_barrier();
    __builtin_amdgcn_sched_barrier(0);
    const char* Ab = lds + ((t & 1) << 16);
    const char* Bb = Ab + 32768;
#pragma unroll
    for (int half = 0; half < 2; ++half) {
      const int kk = (half << 5) + ((lane >> 4) << 3);
      bf16x8 aq[4], bq[4];
#pragma unroll
      for (int nf = 0; nf < 4; ++nf)
        bq[nf] = *(const bf16x8*)(Bb + lds_off((wn << 6) + (nf << 4) + (lane & 15), kk));
#pragma unroll
      for (int mf = 0; mf < 4; ++mf)
        aq[mf] = *(const bf16x8*)(Ab + lds_off((wm << 7) + (mf << 4) + (lane & 15), kk));
      __builtin_amdgcn_s_setprio(1);
#pragma unroll
      for (int mf = 0; mf < 4; ++mf)
#pragma unroll
        for (int nf = 0; nf < 4; ++nf)
          acc[mf][nf] = __builtin_amdgcn_mfma_f32_16x16x32_bf16(aq[mf], bq[nf], acc[mf][nf], 0, 0, 0);
      __builtin_amdgcn_s_setprio(0);
      __builtin_amdgcn_sched_barrier(0);
#pragma unroll
      for (int mf = 0; mf < 4; ++mf)
        aq[mf] = *(const bf16x8*)(Ab + lds_off((wm << 7) + ((mf + 4) << 4) + (lane & 15), kk));
      __builtin_amdgcn_s_setprio(1);
#pragma unroll
      for (int mf = 0; mf < 4; ++mf)
#pragma unroll
        for (int nf = 0; nf < 4; ++nf)
          acc[mf + 4][nf] = __builtin_amdgcn_mfma_f32_16x16x32_bf16(aq[mf], bq[nf], acc[mf + 4][nf], 0, 0, 0);
      __builtin_amdgcn_s_setprio(0);
      __builtin_amdgcn_sched_barrier(0);
    }
    __builtin_amdgcn_s_barrier();   // all waves done reading buf[t&1]
    __builtin_amdgcn_sched_barrier(0);
    if (t + 2 < NT) stage(t + 2);
  }

#pragma unroll
  for (int nf = 0; nf < 4; ++nf) {
    int col = n0 + (wn << 6) + (nf << 4) + (lane & 15);
    float bcol = (!BIAS_ROW && bias) ? bias[col] : 0.0f;
#pragma unroll
    for (int mf = 0; mf < 8; ++mf) {
      f32x4 a = acc[mf][nf];
#pragma unroll
      for (int r = 0; r < 4; ++r) {
        int rowg = m0 + (wm << 7) + (mf << 4) + ((lane >> 4) << 2) + r;
        float bv = BIAS_ROW ? (bias ? bias[rowg] : 0.0f) : bcol;
        float v = a[r] * scale + bv;
        if (do_relu) v = fmaxf(v, 0.0f);
        if (OUT_BF16) ((unsigned short*)Cv)[(size_t)rowg * ldc + col] = f2bf(v);
        else          ((float*)Cv)[(size_t)rowg * ldc + col] = v;
      }
    }
  }
}

extern "C" void kernel_launch(void* const* d_in, const int* in_sizes, int n_in,
                              void* d_out, int out_size, void* d_ws, size_t ws_size,
                              hipStream_t stream) {
  const float* X   = (const float*)d_in[0];
  const float* Y   = (const float*)d_in[1];
  const float* R   = (const float*)d_in[2];
  const float* Wi  = (const float*)d_in[3];
  const float* bi  = (const float*)d_in[4];
  const float* Wo  = (const float*)d_in[5];
  const float* bo  = (const float*)d_in[6];
  const float* Wc  = (const float*)d_in[7];
  const float* bc  = (const float*)d_in[8];
  const float* Wf  = (const float*)d_in[9];
  const float* bf_ = (const float*)d_in[10];
  float* out = (float*)d_out;

  char* ws = (char*)d_ws;
  size_t off = 0;
  auto alloc = [&](size_t b) { char* p = ws + off; off += (b + 255) & ~(size_t)255; return p; };
  unsigned short* Xb   = (unsigned short*)alloc((size_t)S_TOK * DIM  * 2);  // later iqk|oqk z=0
  unsigned short* Yb   = (unsigned short*)alloc((size_t)S_TOK * DIM  * 2);  // later iqk|oqk z=1
  unsigned short* Rb   = (unsigned short*)alloc((size_t)S_TOK * DIM  * 2);
  unsigned short* WiT  = (unsigned short*)alloc((size_t)DIM2 * DIM  * 2);
  unsigned short* WoT  = (unsigned short*)alloc((size_t)DIM2 * DIM  * 2);
  unsigned short* WcT  = (unsigned short*)alloc((size_t)DIM2 * DIM2 * 2);
  unsigned short* WfT  = (unsigned short*)alloc((size_t)OUTN * DIM2 * 2);
  unsigned short* iqT  = (unsigned short*)alloc((size_t)DIM2 * S_TOK * 2);  // later meta0/1+MWT0/1
  unsigned short* oqT0 = (unsigned short*)alloc((size_t)DIM2 * S_TOK * 2);  // later icm0
  unsigned short* oqT1 = (unsigned short*)alloc((size_t)DIM2 * S_TOK * 2);  // later icm1
  unsigned short* icmT0= (unsigned short*)alloc((size_t)DIM2 * S_TOK * 2);
  unsigned short* icmT1= (unsigned short*)alloc((size_t)DIM2 * S_TOK * 2);
  unsigned short* iqk0 = Xb;
  unsigned short* oqk0 = Xb + (size_t)DIM2*DIM2;
  unsigned short* iqk1 = Yb;
  unsigned short* oqk1 = Yb + (size_t)DIM2*DIM2;
  unsigned short* meta0= iqT;
  unsigned short* meta1= iqT + (size_t)DIM2*DIM2;
  unsigned short* MWT0 = iqT + (size_t)2*DIM2*DIM2;
  unsigned short* MWT1 = iqT + (size_t)2*DIM2*DIM2 + (size_t)OUTN*DIM2;
  unsigned short* icm0 = oqT0;
  unsigned short* icm1 = oqT1;

  auto cvt = [&](const float* s, unsigned short* d, int n) {
    int n4 = n >> 2;
    cvt_f32_bf16<<<dim3((n4 + 255) / 256), dim3(256), 0, stream>>>(s, d, n4);
  };
  cvt(X, Xb, S_TOK * DIM);
  cvt(Y, Yb, S_TOK * DIM);
  cvt(R, Rb, S_TOK * DIM);
  transpose_to_bf16<1><<<dim3(DIM2 / 64, DIM  / 64), 256, 0, stream>>>(Wi, WiT, DIM,  DIM2);
  transpose_to_bf16<1><<<dim3(DIM2 / 64, DIM  / 64), 256, 0, stream>>>(Wo, WoT, DIM,  DIM2);
  transpose_to_bf16<1><<<dim3(DIM2 / 64, DIM2 / 64), 256, 0, stream>>>(Wc, WcT, DIM2, DIM2);
  transpose_to_bf16<1><<<dim3(OUTN / 64, DIM2 / 64), 256, 0, stream>>>(Wf, WfT, DIM2, OUTN);

  const float rscale = 0.022097086912079608f;  // 1/sqrt(2048)

  // G1: z=3 -> iqT = (X@Wi+bi)^T ; oqT0 = (Y@Wo+bo)^T ; oqT1 = (R@Wo+bo)^T
  {
    GPtr g{};
    g.A[0] = WiT; g.A[1] = WoT; g.A[2] = WoT;
    g.B[0] = Xb;  g.B[1] = Yb;  g.B[2] = Rb;
    g.bias[0] = bi; g.bias[1] = bo; g.bias[2] = bo;
    g.C[0] = iqT; g.C[1] = oqT0; g.C[2] = oqT1;
    gemm256<0,0,1,1><<<dim3(S_TOK/256, DIM2/256, 3), 512, 0, stream>>>(
        g, DIM, DIM, S_TOK, DIM, 1.f, 0);
  }
  // G2: z=2 -> icmT_z = (cat(X, Y|R)@Wc + bc)^T
  {
    GPtr g{};
    g.A[0] = WcT; g.A[1] = WcT;
    g.B[0] = Xb;  g.B[1] = Xb;
    g.Bk2[0] = Yb; g.Bk2[1] = Rb;
    g.bias[0] = bc; g.bias[1] = bc;
    g.C[0] = icmT0; g.C[1] = icmT1;
    gemm256<0,1,1,1><<<dim3(S_TOK/256, DIM2/256, 2), 512, 0, stream>>>(
        g, DIM2, DIM, S_TOK, DIM2, 1.f, 0);
  }
  // SM: column-softmax all 5 activation maps
  {
    SmTab st{};
    st.T[0] = iqT; st.T[1] = oqT0; st.T[2] = oqT1; st.T[3] = icmT0; st.T[4] = icmT1;
    softmax_cols<<<dim3(S_TOK / 64, 5), dim3(512), 0, stream>>>(st);
  }
  // G3: z=2 -> [iqk_z; oqk_z] = [iqT; oqT_z] @ icmT_z^T   (M=4096, K=8192)
  {
    GPtr g{};
    g.A[0] = iqT; g.A[1] = iqT;
    g.Arow2[0] = oqT0; g.Arow2[1] = oqT1;
    g.B[0] = icmT0; g.B[1] = icmT1;
    g.C[0] = iqk0; g.C[1] = iqk1;
    gemm256<1,0,0,1><<<dim3(DIM2/256, 4096/256, 2), 512, 0, stream>>>(
        g, S_TOK, S_TOK, DIM2, S_TOK, 1.f, 0);
  }
  // T: icm_z = transpose(icmT_z)
  transpose_to_bf16<0><<<dim3(S_TOK / 64, DIM2 / 64), 256, 0, stream>>>(icmT0, icm0, DIM2, S_TOK);
  transpose_to_bf16<0><<<dim3(S_TOK / 64, DIM2 / 64), 256, 0, stream>>>(icmT1, icm1, DIM2, S_TOK);
  // G4: z=2 -> meta_z = relu(iqk_z @ oqk_z^T)   (128^2 kernel, 512 blocks)
  {
    GPtr g{};
    g.A[0] = iqk0; g.A[1] = iqk1;
    g.B[0] = oqk0; g.B[1] = oqk1;
    g.C[0] = meta0; g.C[1] = meta1;
    gemm_nt<0,0,0,1><<<dim3(DIM2/128, DIM2/128, 2), 256, 0, stream>>>(
        g, DIM2, DIM2, DIM2, DIM2, 1.f, 1);
  }
  // G5: z=2 -> MWT_z = (WfT @ meta_z^T) * rscale
  {
    GPtr g{};
    g.A[0] = WfT; g.A[1] = WfT;
    g.B[0] = meta0; g.B[1] = meta1;
    g.C[0] = MWT0; g.C[1] = MWT1;
    gemm_nt<0,0,0,1><<<dim3(DIM2/128, OUTN/128, 2), 256, 0, stream>>>(
        g, DIM2, DIM2, DIM2, DIM2, rscale, 0);
  }
  // G6: z=2 -> out_z = relu(icm_z @ MWT_z^T + bf)   [8192,1024] f32
  {
    GPtr g{};
    g.A[0] = icm0; g.A[1] = icm1;
    g.B[0] = MWT0; g.B[1] = MWT1;
    g.bias[0] = bf_; g.bias[1] = bf_;
    g.C[0] = out; g.C[1] = out + (size_t)S_TOK * OUTN;
    gemm256<0,0,0,0><<<dim3(OUTN/256, S_TOK/256, 2), 512, 0, stream>>>(
        g, DIM2, DIM2, OUTN, DIM2, 1.f, 1);
  }
  (void)in_sizes; (void)n_in; (void)out_size; (void)ws_size;
}

// Round 6
// 953.168 us; speedup vs baseline: 1.0164x; 1.0164x over previous
//
#include <hip/hip_runtime.h>

#define S_TOK 8192
#define DIM   1024
#define DIM2  2048
#define OUTN  1024

typedef __bf16 bf16x8 __attribute__((ext_vector_type(8)));
typedef float  f32x4  __attribute__((ext_vector_type(4)));
typedef short  s16x8  __attribute__((ext_vector_type(8)));
typedef unsigned short u16x4 __attribute__((ext_vector_type(4)));

__device__ __forceinline__ unsigned short f2bf(float x) {
  unsigned u = __builtin_bit_cast(unsigned, x);
  u = (u + 0x7FFFu + ((u >> 16) & 1u)) >> 16;
  return (unsigned short)u;
}
__device__ __forceinline__ float bf2f(unsigned short u) {
  return __builtin_bit_cast(float, (unsigned)u << 16);
}

__device__ __forceinline__ void gld_lds16(const void* g, void* l) {
  auto* g1 = reinterpret_cast<__attribute__((address_space(1))) unsigned*>(
      (unsigned long long)g);
  auto* l3 = reinterpret_cast<__attribute__((address_space(3))) unsigned*>(
      (unsigned long long)l);
  __builtin_amdgcn_global_load_lds(g1, l3, 16, 0, 0);
}

// 3-bit XOR swizzle for a [rows][64] bf16 tile (row stride 128B):
// XOR byte bits [6:4] with (row ^ row>>3)&7. For the fragment-read pattern
// (16 consecutive rows x 4 16B-columns per wave) this spreads each column
// group across all 8 columns -> 8 dwords/bank = b128 floor. Staging keeps the
// LDS write LINEAR and pre-XORs the GLOBAL source k-chunk (involution).
__device__ __forceinline__ int lds_off(int idx, int k) {
  int b = (idx << 7) + (k << 1);
  b ^= ((idx ^ (idx >> 3)) & 7) << 4;
  return b;
}

__global__ __launch_bounds__(256) void cvt_f32_bf16(const float* __restrict__ in,
                                                    unsigned short* __restrict__ out, int n4) {
  int i = blockIdx.x * 256 + threadIdx.x;
  if (i >= n4) return;
  float4 v = ((const float4*)in)[i];
  u16x4 o;
  o[0] = f2bf(v.x); o[1] = f2bf(v.y); o[2] = f2bf(v.z); o[3] = f2bf(v.w);
  *(u16x4*)(out + (size_t)i * 4) = o;
}

// Tiled transpose: in [R,C] (f32 or bf16) -> out [C,R] bf16. 64x64 tiles, 256 thr.
template <int F32IN>
__global__ __launch_bounds__(256) void transpose_to_bf16(const void* __restrict__ in,
                                                         unsigned short* __restrict__ out,
                                                         int R, int C) {
  __shared__ unsigned short t[64 * 64];
  const int r0 = blockIdx.y << 6, c0 = blockIdx.x << 6;
  const int tid = threadIdx.x;
#pragma unroll
  for (int i = 0; i < 2; ++i) {
    int ch = tid + (i << 8);
    int r = ch >> 3, c8 = (ch & 7) << 3;
    s16x8 w;
    if (F32IN) {
      const float* p = (const float*)in + (size_t)(r0 + r) * C + c0 + c8;
      float4 a = *(const float4*)p, b = *(const float4*)(p + 4);
      w[0] = (short)f2bf(a.x); w[1] = (short)f2bf(a.y);
      w[2] = (short)f2bf(a.z); w[3] = (short)f2bf(a.w);
      w[4] = (short)f2bf(b.x); w[5] = (short)f2bf(b.y);
      w[6] = (short)f2bf(b.z); w[7] = (short)f2bf(b.w);
    } else {
      w = *(const s16x8*)((const unsigned short*)in + (size_t)(r0 + r) * C + c0 + c8);
    }
    int sw = ((r ^ (r >> 3)) & 7) << 3;
    *(s16x8*)&t[(r << 6) + (c8 ^ sw)] = w;
  }
  __syncthreads();
#pragma unroll
  for (int i = 0; i < 2; ++i) {
    int ch = tid + (i << 8);
    int c = ch >> 3, r8 = (ch & 7) << 3;
    s16x8 w;
#pragma unroll
    for (int j = 0; j < 8; ++j) {
      int rr = r8 + j;
      w[j] = (short)t[(rr << 6) + (c ^ (((rr ^ (rr >> 3)) & 7) << 3))];
    }
    *(s16x8*)(out + (size_t)(c0 + c) * R + r0 + r8) = w;
  }
}

// Softmax over the ROW axis (2048 feats) of T [2048, S_TOK], per column, in place.
struct SmTab { unsigned short* T[6]; };
__global__ __launch_bounds__(512) void softmax_cols(SmTab tab) {
  unsigned short* T = tab.T[blockIdx.y];
  const int tid = threadIdx.x;
  const int colg = tid & 63, seg = tid >> 6;
  const size_t c = ((size_t)blockIdx.x << 6) + colg;
  float m = -1e30f, s = 0.f;
  for (int n = seg; n < DIM2; n += 8) {
    float v = bf2f(T[(size_t)n * S_TOK + c]);
    float mn = fmaxf(m, v);
    s = s * __expf(m - mn) + __expf(v - mn);
    m = mn;
  }
  __shared__ float redm[512], reds[512];
  redm[tid] = m; reds[tid] = s;
  __syncthreads();
  if (seg == 0) {
    float M = m, S = s;
#pragma unroll
    for (int k = 1; k < 8; ++k) {
      float mk = redm[colg + (k << 6)], sk = reds[colg + (k << 6)];
      float mn = fmaxf(M, mk);
      S = S * __expf(M - mn) + sk * __expf(mk - mn);
      M = mn;
    }
    redm[colg] = M; reds[colg] = 1.0f / S;
  }
  __syncthreads();
  m = redm[colg];
  const float inv = reds[colg];
  for (int n = seg; n < DIM2; n += 8) {
    size_t idx = (size_t)n * S_TOK + c;
    T[idx] = f2bf(__expf(bf2f(T[idx]) - m) * inv);
  }
}

struct GPtr {
  const unsigned short* A[3];
  const unsigned short* Arow2[3];
  const unsigned short* B[3];
  const unsigned short* Bk2[3];
  const float* bias[3];
  void* C[3];
};

// ---------------- 128x128 kernel (small GEMMs: G4, G5) ----------------
template <int ASPLIT, int BSPLIT, int BIAS_ROW, int OUT_BF16>
__global__ __launch_bounds__(256, 3) void gemm_nt(GPtr p, int lda, int ldb, int ldc,
                                                  int K, float scale, int do_relu) {
  __shared__ char lds[32768];
  char* As = lds;
  char* Bs = lds + 16384;
  const int z = blockIdx.z;
  const int tid  = threadIdx.x;
  const int lane = tid & 63;
  const int wave = tid >> 6;
  const int wm = (wave >> 1) << 6;
  const int wn = (wave & 1) << 6;
  const int m0 = blockIdx.y << 7;
  const int n0 = blockIdx.x << 7;

  const unsigned short* Au = p.A[z];
  int mb = m0;
  if (ASPLIT && m0 >= 2048) { Au = p.Arow2[z]; mb = m0 - 2048; }
  const unsigned short* B  = p.B[z];
  const unsigned short* B2 = BSPLIT ? p.Bk2[z] : B;
  const float* bias = p.bias[z];
  void* Cv = p.C[z];

  int srow[4], sgk[4];
#pragma unroll
  for (int i = 0; i < 4; ++i) {
    int c = (wave << 8) + (i << 6) + lane;
    int row = c >> 3, kc = c & 7;
    srow[i] = row;
    sgk[i]  = (kc ^ ((row ^ (row >> 3)) & 7)) << 3;  // pre-swizzled source
  }

  f32x4 acc[4][4];
#pragma unroll
  for (int i = 0; i < 4; ++i)
#pragma unroll
    for (int j = 0; j < 4; ++j) acc[i][j] = {0.f, 0.f, 0.f, 0.f};

  for (int k0 = 0; k0 < K; k0 += 64) {
    const unsigned short* bsrc = B;
    int kb = k0;
    if (BSPLIT && k0 >= DIM) { bsrc = B2; kb = k0 - DIM; }
#pragma unroll
    for (int i = 0; i < 4; ++i) {
      char* dA = As + (((wave << 2) + i) << 10);
      char* dB = Bs + (((wave << 2) + i) << 10);
      gld_lds16(Au   + (size_t)(mb + srow[i]) * lda + k0 + sgk[i], dA);
      gld_lds16(bsrc + (size_t)(n0 + srow[i]) * ldb + kb + sgk[i], dB);
    }
    __syncthreads();
#pragma unroll
    for (int ks = 0; ks < 2; ++ks) {
      bf16x8 af[4], bfr[4];
      int kk = (ks << 5) + ((lane >> 4) << 3);
#pragma unroll
      for (int t = 0; t < 4; ++t) {
        af[t]  = *(const bf16x8*)(As + lds_off(wm + (t << 4) + (lane & 15), kk));
        bfr[t] = *(const bf16x8*)(Bs + lds_off(wn + (t << 4) + (lane & 15), kk));
      }
#pragma unroll
      for (int mt = 0; mt < 4; ++mt)
#pragma unroll
        for (int nt = 0; nt < 4; ++nt)
          acc[mt][nt] = __builtin_amdgcn_mfma_f32_16x16x32_bf16(af[mt], bfr[nt], acc[mt][nt], 0, 0, 0);
    }
    __syncthreads();
  }

#pragma unroll
  for (int nt = 0; nt < 4; ++nt) {
    int col = n0 + wn + (nt << 4) + (lane & 15);
    float bcol = (!BIAS_ROW && bias) ? bias[col] : 0.0f;
#pragma unroll
    for (int mt = 0; mt < 4; ++mt) {
      f32x4 a = acc[mt][nt];
#pragma unroll
      for (int r = 0; r < 4; ++r) {
        int rowg = m0 + wm + (mt << 4) + ((lane >> 4) << 2) + r;
        float bv = BIAS_ROW ? (bias ? bias[rowg] : 0.0f) : bcol;
        float v = a[r] * scale + bv;
        if (do_relu) v = fmaxf(v, 0.0f);
        if (OUT_BF16) ((unsigned short*)Cv)[(size_t)rowg * ldc + col] = f2bf(v);
        else          ((float*)Cv)[(size_t)rowg * ldc + col] = v;
      }
    }
  }
}

// ---------------- 256x256 counted-vmcnt pipelined kernel ----------------
// BM=BN=256, BK=64, 512 thr = 8 waves (2M x 4N), per-wave 128x64 output.
// LDS 128KB double-buffered; 2-deep prefetch with counted s_waitcnt vmcnt(8)
// across raw s_barrier. Tile body is ONE schedulable region (no intra-tile
// fences): compiler interleaves the 24 ds_read_b128 with the 64 MFMAs using
// fine-grained lgkmcnt (m97-verified behavior).
template <int ASPLIT, int BSPLIT, int BIAS_ROW, int OUT_BF16>
__global__ __launch_bounds__(512, 2) void gemm256(GPtr p, int lda, int ldb, int ldc,
                                                  int K, float scale, int do_relu) {
  __shared__ char lds[131072];
  const int z = blockIdx.z;
  const int tid  = threadIdx.x;
  const int lane = tid & 63;
  const int wave = tid >> 6;      // 0..7
  const int wm   = wave >> 2;     // 0..1  (M half)
  const int wn   = wave & 3;      // 0..3  (N quarter)

  // bijective XCD-chunked swizzle of the (x,y) block id (nwg % 8 == 0)
  const int gx = gridDim.x;
  const int nwg = gx * gridDim.y;
  int id = blockIdx.y * gx + blockIdx.x;
  id = (id & 7) * (nwg >> 3) + (id >> 3);
  const int n0 = (id % gx) << 8;
  const int m0 = (id / gx) << 8;

  const unsigned short* Au = p.A[z];
  int mb = m0;
  if (ASPLIT && m0 >= 2048) { Au = p.Arow2[z]; mb = m0 - 2048; }
  const unsigned short* Bp = p.B[z];
  const unsigned short* B2 = BSPLIT ? p.Bk2[z] : Bp;
  const float* bias = p.bias[z];
  void* Cv = p.C[z];

  // staging: A tile 256x64 = 2048 16B-chunks; chunk c = i*512 + tid.
  int srow[4], sgk[4];
#pragma unroll
  for (int i = 0; i < 4; ++i) {
    int c = (i << 9) + tid;
    int row = c >> 3, kc = c & 7;
    srow[i] = row;
    sgk[i]  = (kc ^ ((row ^ (row >> 3)) & 7)) << 3;  // pre-swizzled source
  }

  auto stage = [&](int t) {
    const int k0 = t << 6;
    char* Abase = lds + ((t & 1) << 16);
    char* Bbase = Abase + 32768;
    const unsigned short* bsrc = Bp;
    int kb = k0;
    if (BSPLIT && k0 >= DIM) { bsrc = B2; kb = k0 - DIM; }
#pragma unroll
    for (int i = 0; i < 4; ++i) {
      gld_lds16(Au   + (size_t)(mb + srow[i]) * lda + k0 + sgk[i],
                Abase + (i << 13) + (wave << 10));
      gld_lds16(bsrc + (size_t)(n0 + srow[i]) * ldb + kb + sgk[i],
                Bbase + (i << 13) + (wave << 10));
    }
  };

  f32x4 acc[8][4];
#pragma unroll
  for (int i = 0; i < 8; ++i)
#pragma unroll
    for (int j = 0; j < 4; ++j) acc[i][j] = {0.f, 0.f, 0.f, 0.f};

  const int NT = K >> 6;  // >= 2, even
  stage(0);
  stage(1);

  for (int t = 0; t < NT; ++t) {
    if (t + 1 < NT) asm volatile("s_waitcnt vmcnt(8)" ::: "memory");
    else            asm volatile("s_waitcnt vmcnt(0)" ::: "memory");
    __builtin_amdgcn_s_barrier();
    __builtin_amdgcn_sched_barrier(0);
    const char* Ab = lds + ((t & 1) << 16);
    const char* Bb = Ab + 32768;
    bf16x8 aq0[8], bq0[4], aq1[8], bq1[4];
    const int kkl = (lane >> 4) << 3;
#pragma unroll
    for (int nf = 0; nf < 4; ++nf)
      bq0[nf] = *(const bf16x8*)(Bb + lds_off((wn << 6) + (nf << 4) + (lane & 15), kkl));
#pragma unroll
    for (int mf = 0; mf < 8; ++mf)
      aq0[mf] = *(const bf16x8*)(Ab + lds_off((wm << 7) + (mf << 4) + (lane & 15), kkl));
#pragma unroll
    for (int nf = 0; nf < 4; ++nf)
      bq1[nf] = *(const bf16x8*)(Bb + lds_off((wn << 6) + (nf << 4) + (lane & 15), 32 + kkl));
#pragma unroll
    for (int mf = 0; mf < 8; ++mf)
      aq1[mf] = *(const bf16x8*)(Ab + lds_off((wm << 7) + (mf << 4) + (lane & 15), 32 + kkl));
#pragma unroll
    for (int mf = 0; mf < 8; ++mf)
#pragma unroll
      for (int nf = 0; nf < 4; ++nf)
        acc[mf][nf] = __builtin_amdgcn_mfma_f32_16x16x32_bf16(aq0[mf], bq0[nf], acc[mf][nf], 0, 0, 0);
#pragma unroll
    for (int mf = 0; mf < 8; ++mf)
#pragma unroll
      for (int nf = 0; nf < 4; ++nf)
        acc[mf][nf] = __builtin_amdgcn_mfma_f32_16x16x32_bf16(aq1[mf], bq1[nf], acc[mf][nf], 0, 0, 0);
    __builtin_amdgcn_sched_barrier(0);
    __builtin_amdgcn_s_barrier();   // all waves done reading buf[t&1]
    __builtin_amdgcn_sched_barrier(0);
    if (t + 2 < NT) stage(t + 2);
  }

#pragma unroll
  for (int nf = 0; nf < 4; ++nf) {
    int col = n0 + (wn << 6) + (nf << 4) + (lane & 15);
    float bcol = (!BIAS_ROW && bias) ? bias[col] : 0.0f;
#pragma unroll
    for (int mf = 0; mf < 8; ++mf) {
      f32x4 a = acc[mf][nf];
#pragma unroll
      for (int r = 0; r < 4; ++r) {
        int rowg = m0 + (wm << 7) + (mf << 4) + ((lane >> 4) << 2) + r;
        float bv = BIAS_ROW ? (bias ? bias[rowg] : 0.0f) : bcol;
        float v = a[r] * scale + bv;
        if (do_relu) v = fmaxf(v, 0.0f);
        if (OUT_BF16) ((unsigned short*)Cv)[(size_t)rowg * ldc + col] = f2bf(v);
        else          ((float*)Cv)[(size_t)rowg * ldc + col] = v;
      }
    }
  }
}

extern "C" void kernel_launch(void* const* d_in, const int* in_sizes, int n_in,
                              void* d_out, int out_size, void* d_ws, size_t ws_size,
                              hipStream_t stream) {
  const float* X   = (const float*)d_in[0];
  const float* Y   = (const float*)d_in[1];
  const float* R   = (const float*)d_in[2];
  const float* Wi  = (const float*)d_in[3];
  const float* bi  = (const float*)d_in[4];
  const float* Wo  = (const float*)d_in[5];
  const float* bo  = (const float*)d_in[6];
  const float* Wc  = (const float*)d_in[7];
  const float* bc  = (const float*)d_in[8];
  const float* Wf  = (const float*)d_in[9];
  const float* bf_ = (const float*)d_in[10];
  float* out = (float*)d_out;

  char* ws = (char*)d_ws;
  size_t off = 0;
  auto alloc = [&](size_t b) { char* p = ws + off; off += (b + 255) & ~(size_t)255; return p; };
  unsigned short* Xb   = (unsigned short*)alloc((size_t)S_TOK * DIM  * 2);  // later iqk|oqk z=0
  unsigned short* Yb   = (unsigned short*)alloc((size_t)S_TOK * DIM  * 2);  // later iqk|oqk z=1
  unsigned short* Rb   = (unsigned short*)alloc((size_t)S_TOK * DIM  * 2);
  unsigned short* WiT  = (unsigned short*)alloc((size_t)DIM2 * DIM  * 2);
  unsigned short* WoT  = (unsigned short*)alloc((size_t)DIM2 * DIM  * 2);
  unsigned short* WcT  = (unsigned short*)alloc((size_t)DIM2 * DIM2 * 2);
  unsigned short* WfT  = (unsigned short*)alloc((size_t)OUTN * DIM2 * 2);
  unsigned short* iqT  = (unsigned short*)alloc((size_t)DIM2 * S_TOK * 2);  // later meta0/1+MWT0/1
  unsigned short* oqT0 = (unsigned short*)alloc((size_t)DIM2 * S_TOK * 2);  // later icm0
  unsigned short* oqT1 = (unsigned short*)alloc((size_t)DIM2 * S_TOK * 2);  // later icm1
  unsigned short* icmT0= (unsigned short*)alloc((size_t)DIM2 * S_TOK * 2);
  unsigned short* icmT1= (unsigned short*)alloc((size_t)DIM2 * S_TOK * 2);
  unsigned short* iqk0 = Xb;
  unsigned short* oqk0 = Xb + (size_t)DIM2*DIM2;
  unsigned short* iqk1 = Yb;
  unsigned short* oqk1 = Yb + (size_t)DIM2*DIM2;
  unsigned short* meta0= iqT;
  unsigned short* meta1= iqT + (size_t)DIM2*DIM2;
  unsigned short* MWT0 = iqT + (size_t)2*DIM2*DIM2;
  unsigned short* MWT1 = iqT + (size_t)2*DIM2*DIM2 + (size_t)OUTN*DIM2;
  unsigned short* icm0 = oqT0;
  unsigned short* icm1 = oqT1;

  auto cvt = [&](const float* s, unsigned short* d, int n) {
    int n4 = n >> 2;
    cvt_f32_bf16<<<dim3((n4 + 255) / 256), dim3(256), 0, stream>>>(s, d, n4);
  };
  cvt(X, Xb, S_TOK * DIM);
  cvt(Y, Yb, S_TOK * DIM);
  cvt(R, Rb, S_TOK * DIM);
  transpose_to_bf16<1><<<dim3(DIM2 / 64, DIM  / 64), 256, 0, stream>>>(Wi, WiT, DIM,  DIM2);
  transpose_to_bf16<1><<<dim3(DIM2 / 64, DIM  / 64), 256, 0, stream>>>(Wo, WoT, DIM,  DIM2);
  transpose_to_bf16<1><<<dim3(DIM2 / 64, DIM2 / 64), 256, 0, stream>>>(Wc, WcT, DIM2, DIM2);
  transpose_to_bf16<1><<<dim3(OUTN / 64, DIM2 / 64), 256, 0, stream>>>(Wf, WfT, DIM2, OUTN);

  const float rscale = 0.022097086912079608f;  // 1/sqrt(2048)

  // G1: z=3 -> iqT = (X@Wi+bi)^T ; oqT0 = (Y@Wo+bo)^T ; oqT1 = (R@Wo+bo)^T
  {
    GPtr g{};
    g.A[0] = WiT; g.A[1] = WoT; g.A[2] = WoT;
    g.B[0] = Xb;  g.B[1] = Yb;  g.B[2] = Rb;
    g.bias[0] = bi; g.bias[1] = bo; g.bias[2] = bo;
    g.C[0] = iqT; g.C[1] = oqT0; g.C[2] = oqT1;
    gemm256<0,0,1,1><<<dim3(S_TOK/256, DIM2/256, 3), 512, 0, stream>>>(
        g, DIM, DIM, S_TOK, DIM, 1.f, 0);
  }
  // G2: z=2 -> icmT_z = (cat(X, Y|R)@Wc + bc)^T
  {
    GPtr g{};
    g.A[0] = WcT; g.A[1] = WcT;
    g.B[0] = Xb;  g.B[1] = Xb;
    g.Bk2[0] = Yb; g.Bk2[1] = Rb;
    g.bias[0] = bc; g.bias[1] = bc;
    g.C[0] = icmT0; g.C[1] = icmT1;
    gemm256<0,1,1,1><<<dim3(S_TOK/256, DIM2/256, 2), 512, 0, stream>>>(
        g, DIM2, DIM, S_TOK, DIM2, 1.f, 0);
  }
  // SM: column-softmax all 5 activation maps
  {
    SmTab st{};
    st.T[0] = iqT; st.T[1] = oqT0; st.T[2] = oqT1; st.T[3] = icmT0; st.T[4] = icmT1;
    softmax_cols<<<dim3(S_TOK / 64, 5), dim3(512), 0, stream>>>(st);
  }
  // G3: z=2 -> [iqk_z; oqk_z] = [iqT; oqT_z] @ icmT_z^T   (M=4096, K=8192)
  {
    GPtr g{};
    g.A[0] = iqT; g.A[1] = iqT;
    g.Arow2[0] = oqT0; g.Arow2[1] = oqT1;
    g.B[0] = icmT0; g.B[1] = icmT1;
    g.C[0] = iqk0; g.C[1] = iqk1;
    gemm256<1,0,0,1><<<dim3(DIM2/256, 4096/256, 2), 512, 0, stream>>>(
        g, S_TOK, S_TOK, DIM2, S_TOK, 1.f, 0);
  }
  // T: icm_z = transpose(icmT_z)
  transpose_to_bf16<0><<<dim3(S_TOK / 64, DIM2 / 64), 256, 0, stream>>>(icmT0, icm0, DIM2, S_TOK);
  transpose_to_bf16<0><<<dim3(S_TOK / 64, DIM2 / 64), 256, 0, stream>>>(icmT1, icm1, DIM2, S_TOK);
  // G4: z=2 -> meta_z = relu(iqk_z @ oqk_z^T)
  {
    GPtr g{};
    g.A[0] = iqk0; g.A[1] = iqk1;
    g.B[0] = oqk0; g.B[1] = oqk1;
    g.C[0] = meta0; g.C[1] = meta1;
    gemm_nt<0,0,0,1><<<dim3(DIM2/128, DIM2/128, 2), 256, 0, stream>>>(
        g, DIM2, DIM2, DIM2, DIM2, 1.f, 1);
  }
  // G5: z=2 -> MWT_z = (WfT @ meta_z^T) * rscale
  {
    GPtr g{};
    g.A[0] = WfT; g.A[1] = WfT;
    g.B[0] = meta0; g.B[1] = meta1;
    g.C[0] = MWT0; g.C[1] = MWT1;
    gemm_nt<0,0,0,1><<<dim3(DIM2/128, OUTN/128, 2), 256, 0, stream>>>(
        g, DIM2, DIM2, DIM2, DIM2, rscale, 0);
  }
  // G6: z=2 -> out_z = relu(icm_z @ MWT_z^T + bf)   [8192,1024] f32
  {
    GPtr g{};
    g.A[0] = icm0; g.A[1] = icm1;
    g.B[0] = MWT0; g.B[1] = MWT1;
    g.bias[0] = bf_; g.bias[1] = bf_;
    g.C[0] = out; g.C[1] = out + (size_t)S_TOK * OUTN;
    gemm256<0,0,0,0><<<dim3(OUTN/256, S_TOK/256, 2), 512, 0, stream>>>(
        g, DIM2, DIM2, OUTN, DIM2, 1.f, 1);
  }
  (void)in_sizes; (void)n_in; (void)out_size; (void)ws_size;
}

// Round 7
// 928.851 us; speedup vs baseline: 1.0430x; 1.0262x over previous
//
#include <hip/hip_runtime.h>

#define S_TOK 8192
#define DIM   1024
#define DIM2  2048
#define OUTN  1024

typedef __bf16 bf16x8 __attribute__((ext_vector_type(8)));
typedef float  f32x4  __attribute__((ext_vector_type(4)));
typedef short  s16x8  __attribute__((ext_vector_type(8)));
typedef unsigned short u16x4 __attribute__((ext_vector_type(4)));

__device__ __forceinline__ unsigned short f2bf(float x) {
  unsigned u = __builtin_bit_cast(unsigned, x);
  u = (u + 0x7FFFu + ((u >> 16) & 1u)) >> 16;
  return (unsigned short)u;
}
__device__ __forceinline__ float bf2f(unsigned short u) {
  return __builtin_bit_cast(float, (unsigned)u << 16);
}

__device__ __forceinline__ void gld_lds16(const void* g, void* l) {
  auto* g1 = reinterpret_cast<__attribute__((address_space(1))) unsigned*>(
      (unsigned long long)g);
  auto* l3 = reinterpret_cast<__attribute__((address_space(3))) unsigned*>(
      (unsigned long long)l);
  __builtin_amdgcn_global_load_lds(g1, l3, 16, 0, 0);
}

// 128^2-kernel swizzle for [rows][64] bf16 tiles (row stride 128B).
__device__ __forceinline__ int lds_off(int idx, int k) {
  int b = (idx << 7) + (k << 1);
  b ^= ((idx ^ (idx >> 3)) & 7) << 4;
  return b;
}

__global__ __launch_bounds__(256) void cvt_f32_bf16(const float* __restrict__ in,
                                                    unsigned short* __restrict__ out, int n4) {
  int i = blockIdx.x * 256 + threadIdx.x;
  if (i >= n4) return;
  float4 v = ((const float4*)in)[i];
  u16x4 o;
  o[0] = f2bf(v.x); o[1] = f2bf(v.y); o[2] = f2bf(v.z); o[3] = f2bf(v.w);
  *(u16x4*)(out + (size_t)i * 4) = o;
}

// Tiled transpose: in [R,C] (f32 or bf16) -> out [C,R] bf16. 64x64 tiles, 256 thr.
template <int F32IN>
__global__ __launch_bounds__(256) void transpose_to_bf16(const void* __restrict__ in,
                                                         unsigned short* __restrict__ out,
                                                         int R, int C) {
  __shared__ unsigned short t[64 * 64];
  const int r0 = blockIdx.y << 6, c0 = blockIdx.x << 6;
  const int tid = threadIdx.x;
#pragma unroll
  for (int i = 0; i < 2; ++i) {
    int ch = tid + (i << 8);
    int r = ch >> 3, c8 = (ch & 7) << 3;
    s16x8 w;
    if (F32IN) {
      const float* p = (const float*)in + (size_t)(r0 + r) * C + c0 + c8;
      float4 a = *(const float4*)p, b = *(const float4*)(p + 4);
      w[0] = (short)f2bf(a.x); w[1] = (short)f2bf(a.y);
      w[2] = (short)f2bf(a.z); w[3] = (short)f2bf(a.w);
      w[4] = (short)f2bf(b.x); w[5] = (short)f2bf(b.y);
      w[6] = (short)f2bf(b.z); w[7] = (short)f2bf(b.w);
    } else {
      w = *(const s16x8*)((const unsigned short*)in + (size_t)(r0 + r) * C + c0 + c8);
    }
    int sw = ((r ^ (r >> 3)) & 7) << 3;
    *(s16x8*)&t[(r << 6) + (c8 ^ sw)] = w;
  }
  __syncthreads();
#pragma unroll
  for (int i = 0; i < 2; ++i) {
    int ch = tid + (i << 8);
    int c = ch >> 3, r8 = (ch & 7) << 3;
    s16x8 w;
#pragma unroll
    for (int j = 0; j < 8; ++j) {
      int rr = r8 + j;
      w[j] = (short)t[(rr << 6) + (c ^ (((rr ^ (rr >> 3)) & 7) << 3))];
    }
    *(s16x8*)(out + (size_t)(c0 + c) * R + r0 + r8) = w;
  }
}

// Softmax over the ROW axis (2048 feats) of T [2048, S_TOK], per column, in place.
struct SmTab { unsigned short* T[6]; };
__global__ __launch_bounds__(512) void softmax_cols(SmTab tab) {
  unsigned short* T = tab.T[blockIdx.y];
  const int tid = threadIdx.x;
  const int colg = tid & 63, seg = tid >> 6;
  const size_t c = ((size_t)blockIdx.x << 6) + colg;
  float m = -1e30f, s = 0.f;
  for (int n = seg; n < DIM2; n += 8) {
    float v = bf2f(T[(size_t)n * S_TOK + c]);
    float mn = fmaxf(m, v);
    s = s * __expf(m - mn) + __expf(v - mn);
    m = mn;
  }
  __shared__ float redm[512], reds[512];
  redm[tid] = m; reds[tid] = s;
  __syncthreads();
  if (seg == 0) {
    float M = m, S = s;
#pragma unroll
    for (int k = 1; k < 8; ++k) {
      float mk = redm[colg + (k << 6)], sk = reds[colg + (k << 6)];
      float mn = fmaxf(M, mk);
      S = S * __expf(M - mn) + sk * __expf(mk - mn);
      M = mn;
    }
    redm[colg] = M; reds[colg] = 1.0f / S;
  }
  __syncthreads();
  m = redm[colg];
  const float inv = reds[colg];
  for (int n = seg; n < DIM2; n += 8) {
    size_t idx = (size_t)n * S_TOK + c;
    T[idx] = f2bf(__expf(bf2f(T[idx]) - m) * inv);
  }
}

struct GPtr {
  const unsigned short* A[3];
  const unsigned short* Arow2[3];
  const unsigned short* B[3];
  const unsigned short* Bk2[3];
  const float* bias[3];
  void* C[3];
};

// ---------------- 128x128 kernel (small GEMMs: G4, G5) ----------------
template <int ASPLIT, int BSPLIT, int BIAS_ROW, int OUT_BF16>
__global__ __launch_bounds__(256, 3) void gemm_nt(GPtr p, int lda, int ldb, int ldc,
                                                  int K, float scale, int do_relu) {
  __shared__ __align__(16) char lds[32768];
  char* As = lds;
  char* Bs = lds + 16384;
  const int z = blockIdx.z;
  const int tid  = threadIdx.x;
  const int lane = tid & 63;
  const int wave = tid >> 6;
  const int wm = (wave >> 1) << 6;
  const int wn = (wave & 1) << 6;
  const int m0 = blockIdx.y << 7;
  const int n0 = blockIdx.x << 7;

  const unsigned short* Au = p.A[z];
  int mb = m0;
  if (ASPLIT && m0 >= 2048) { Au = p.Arow2[z]; mb = m0 - 2048; }
  const unsigned short* B  = p.B[z];
  const unsigned short* B2 = BSPLIT ? p.Bk2[z] : B;
  const float* bias = p.bias[z];
  void* Cv = p.C[z];

  int srow[4], sgk[4];
#pragma unroll
  for (int i = 0; i < 4; ++i) {
    int c = (wave << 8) + (i << 6) + lane;
    int row = c >> 3, kc = c & 7;
    srow[i] = row;
    sgk[i]  = (kc ^ ((row ^ (row >> 3)) & 7)) << 3;
  }

  f32x4 acc[4][4];
#pragma unroll
  for (int i = 0; i < 4; ++i)
#pragma unroll
    for (int j = 0; j < 4; ++j) acc[i][j] = {0.f, 0.f, 0.f, 0.f};

  for (int k0 = 0; k0 < K; k0 += 64) {
    const unsigned short* bsrc = B;
    int kb = k0;
    if (BSPLIT && k0 >= DIM) { bsrc = B2; kb = k0 - DIM; }
#pragma unroll
    for (int i = 0; i < 4; ++i) {
      char* dA = As + (((wave << 2) + i) << 10);
      char* dB = Bs + (((wave << 2) + i) << 10);
      gld_lds16(Au   + (size_t)(mb + srow[i]) * lda + k0 + sgk[i], dA);
      gld_lds16(bsrc + (size_t)(n0 + srow[i]) * ldb + kb + sgk[i], dB);
    }
    __syncthreads();
#pragma unroll
    for (int ks = 0; ks < 2; ++ks) {
      bf16x8 af[4], bfr[4];
      int kk = (ks << 5) + ((lane >> 4) << 3);
#pragma unroll
      for (int t = 0; t < 4; ++t) {
        af[t]  = *(const bf16x8*)(As + lds_off(wm + (t << 4) + (lane & 15), kk));
        bfr[t] = *(const bf16x8*)(Bs + lds_off(wn + (t << 4) + (lane & 15), kk));
      }
#pragma unroll
      for (int mt = 0; mt < 4; ++mt)
#pragma unroll
        for (int nt = 0; nt < 4; ++nt)
          acc[mt][nt] = __builtin_amdgcn_mfma_f32_16x16x32_bf16(af[mt], bfr[nt], acc[mt][nt], 0, 0, 0);
    }
    __syncthreads();
  }

#pragma unroll
  for (int nt = 0; nt < 4; ++nt) {
    int col = n0 + wn + (nt << 4) + (lane & 15);
    float bcol = (!BIAS_ROW && bias) ? bias[col] : 0.0f;
#pragma unroll
    for (int mt = 0; mt < 4; ++mt) {
      f32x4 a = acc[mt][nt];
#pragma unroll
      for (int r = 0; r < 4; ++r) {
        int rowg = m0 + wm + (mt << 4) + ((lane >> 4) << 2) + r;
        float bv = BIAS_ROW ? (bias ? bias[rowg] : 0.0f) : bcol;
        float v = a[r] * scale + bv;
        if (do_relu) v = fmaxf(v, 0.0f);
        if (OUT_BF16) ((unsigned short*)Cv)[(size_t)rowg * ldc + col] = f2bf(v);
        else          ((float*)Cv)[(size_t)rowg * ldc + col] = v;
      }
    }
  }
}

// ---------------- 256x256 8-phase counted-vmcnt kernel ----------------
// BM=BN=256, BK=64, 8 waves (2M x 4N), per-wave 128x64 output.
// LDS per K-tile buffer: A[2 k-halves][256][32] + B[2 k-halves][256][32]
// (4 units x 16KB), double-buffered = 128KB. Per tile 4 phases =
// (k-half x m-half): each {stage 1 unit of t+1 || ds_read subtile ||
// barrier/lgkmcnt || setprio-wrapped 16 MFMA || barrier}. Counted
// s_waitcnt vmcnt(6) at phases 0 and 2 only (steady state: <=10 loads
// outstanding, oldest 4 must land); last tile drains 4 -> 0.
// Read swizzle: col16 ^= (row>>1)&3 (conflict-free per octet), realized as
// pre-swizzled GLOBAL source + swizzled read; LDS DMA dest stays linear.
template <int ASPLIT, int BSPLIT, int BIAS_ROW, int OUT_BF16>
__global__ __launch_bounds__(512, 2) void gemm256(GPtr p, int lda, int ldb, int ldc,
                                                  int K, float scale, int do_relu) {
  __shared__ __align__(16) char lds[131072];
  const int z = blockIdx.z;
  const int tid  = threadIdx.x;
  const int lane = tid & 63;
  const int wave = tid >> 6;      // 0..7
  const int wm   = wave >> 2;     // 0..1  (M half)
  const int wn   = wave & 3;      // 0..3  (N quarter)

  // bijective XCD-chunked swizzle of the (x,y) block id (nwg % 8 == 0)
  const int gx = gridDim.x;
  const int nwg = gx * gridDim.y;
  int id = blockIdx.y * gx + blockIdx.x;
  id = (id & 7) * (nwg >> 3) + (id >> 3);
  const int n0 = (id % gx) << 8;
  const int m0 = (id / gx) << 8;

  const unsigned short* Au = p.A[z];
  int mb = m0;
  if (ASPLIT && m0 >= 2048) { Au = p.Arow2[z]; mb = m0 - 2048; }
  const unsigned short* Bp = p.B[z];
  const unsigned short* B2 = BSPLIT ? p.Bk2[z] : Bp;
  const float* bias = p.bias[z];
  void* Cv = p.C[z];

  const int NT = K >> 6;

  // staging geometry: one unit = 16KB = 1024 chunks; per thread 2 chunks
  // c = i*512 + wave*64 + lane -> row = c>>2, col16 = lane&3.
  // source k pre-XORed so the linear DMA write realizes the read swizzle.
  int srow_[2], skel_[2];
#pragma unroll
  for (int i = 0; i < 2; ++i) {
    int row = (i << 7) + (wave << 4) + (lane >> 2);
    srow_[i] = row;
    skel_[i] = ((lane & 3) ^ ((row >> 1) & 3)) << 3;
  }

  auto stage_unit = [&](int t, int u) {
    const int k0 = t << 6;
    const int h  = u >> 1;   // k-half
    char* base = lds + ((t & 1) << 16) + ((u & 1) << 15) + (h << 14) + (wave << 10);
    if (u & 1) {  // B unit
      const unsigned short* bsrc = Bp;
      int kb = k0;
      if (BSPLIT && k0 >= DIM) { bsrc = B2; kb = k0 - DIM; }
#pragma unroll
      for (int i = 0; i < 2; ++i)
        gld_lds16(bsrc + (size_t)(n0 + srow_[i]) * ldb + kb + (h << 5) + skel_[i],
                  base + (i << 13));
    } else {      // A unit
#pragma unroll
      for (int i = 0; i < 2; ++i)
        gld_lds16(Au + (size_t)(mb + srow_[i]) * lda + k0 + (h << 5) + skel_[i],
                  base + (i << 13));
    }
  };

  auto rdA = [&](const char* buf, int h, int mf) -> bf16x8 {
    int row = (wm << 7) + (mf << 4) + (lane & 15);
    int col = (lane >> 4) ^ ((row >> 1) & 3);
    return *(const bf16x8*)(buf + (h << 14) + (row << 6) + (col << 4));
  };
  auto rdB = [&](const char* buf, int h, int nf) -> bf16x8 {
    int row = (wn << 6) + (nf << 4) + (lane & 15);
    int col = (lane >> 4) ^ ((row >> 1) & 3);
    return *(const bf16x8*)(buf + 32768 + (h << 14) + (row << 6) + (col << 4));
  };

  f32x4 acc[8][4];
#pragma unroll
  for (int i = 0; i < 8; ++i)
#pragma unroll
    for (int j = 0; j < 4; ++j) acc[i][j] = {0.f, 0.f, 0.f, 0.f};

  // prologue: all 4 units of tile 0
  stage_unit(0, 0); stage_unit(0, 1); stage_unit(0, 2); stage_unit(0, 3);

  for (int t = 0; t < NT; ++t) {
    const char* buf = lds + ((t & 1) << 16);
    const bool more = (t + 1 < NT);
    bf16x8 aq[4], bq[4];

    // ---- phase 0: k-half 0, m-frags 0-3 ----
    if (more) { stage_unit(t + 1, 0); asm volatile("s_waitcnt vmcnt(6)" ::: "memory"); }
    else      { asm volatile("s_waitcnt vmcnt(4)" ::: "memory"); }
    __builtin_amdgcn_s_barrier();
    __builtin_amdgcn_sched_barrier(0);
#pragma unroll
    for (int nf = 0; nf < 4; ++nf) bq[nf] = rdB(buf, 0, nf);
#pragma unroll
    for (int mf = 0; mf < 4; ++mf) aq[mf] = rdA(buf, 0, mf);
    asm volatile("s_waitcnt lgkmcnt(0)" ::: "memory");
    __builtin_amdgcn_sched_barrier(0);
    __builtin_amdgcn_s_setprio(1);
#pragma unroll
    for (int mf = 0; mf < 4; ++mf)
#pragma unroll
      for (int nf = 0; nf < 4; ++nf)
        acc[mf][nf] = __builtin_amdgcn_mfma_f32_16x16x32_bf16(aq[mf], bq[nf], acc[mf][nf], 0, 0, 0);
    __builtin_amdgcn_s_setprio(0);
    __builtin_amdgcn_sched_barrier(0);
    __builtin_amdgcn_s_barrier();

    // ---- phase 1: k-half 0, m-frags 4-7 (reuse bq) ----
#pragma unroll
    for (int mf = 0; mf < 4; ++mf) aq[mf] = rdA(buf, 0, mf + 4);
    if (more) stage_unit(t + 1, 1);
    asm volatile("s_waitcnt lgkmcnt(0)" ::: "memory");
    __builtin_amdgcn_sched_barrier(0);
    __builtin_amdgcn_s_setprio(1);
#pragma unroll
    for (int mf = 0; mf < 4; ++mf)
#pragma unroll
      for (int nf = 0; nf < 4; ++nf)
        acc[mf + 4][nf] = __builtin_amdgcn_mfma_f32_16x16x32_bf16(aq[mf], bq[nf], acc[mf + 4][nf], 0, 0, 0);
    __builtin_amdgcn_s_setprio(0);
    __builtin_amdgcn_sched_barrier(0);
    __builtin_amdgcn_s_barrier();

    // ---- phase 2: k-half 1, m-frags 0-3 ----
    if (more) { stage_unit(t + 1, 2); asm volatile("s_waitcnt vmcnt(6)" ::: "memory"); }
    else      { asm volatile("s_waitcnt vmcnt(0)" ::: "memory"); }
    __builtin_amdgcn_s_barrier();
    __builtin_amdgcn_sched_barrier(0);
#pragma unroll
    for (int nf = 0; nf < 4; ++nf) bq[nf] = rdB(buf, 1, nf);
#pragma unroll
    for (int mf = 0; mf < 4; ++mf) aq[mf] = rdA(buf, 1, mf);
    asm volatile("s_waitcnt lgkmcnt(0)" ::: "memory");
    __builtin_amdgcn_sched_barrier(0);
    __builtin_amdgcn_s_setprio(1);
#pragma unroll
    for (int mf = 0; mf < 4; ++mf)
#pragma unroll
      for (int nf = 0; nf < 4; ++nf)
        acc[mf][nf] = __builtin_amdgcn_mfma_f32_16x16x32_bf16(aq[mf], bq[nf], acc[mf][nf], 0, 0, 0);
    __builtin_amdgcn_s_setprio(0);
    __builtin_amdgcn_sched_barrier(0);
    __builtin_amdgcn_s_barrier();

    // ---- phase 3: k-half 1, m-frags 4-7 (reuse bq) ----
#pragma unroll
    for (int mf = 0; mf < 4; ++mf) aq[mf] = rdA(buf, 1, mf + 4);
    if (more) stage_unit(t + 1, 3);
    asm volatile("s_waitcnt lgkmcnt(0)" ::: "memory");
    __builtin_amdgcn_sched_barrier(0);
    __builtin_amdgcn_s_setprio(1);
#pragma unroll
    for (int mf = 0; mf < 4; ++mf)
#pragma unroll
      for (int nf = 0; nf < 4; ++nf)
        acc[mf + 4][nf] = __builtin_amdgcn_mfma_f32_16x16x32_bf16(aq[mf], bq[nf], acc[mf + 4][nf], 0, 0, 0);
    __builtin_amdgcn_s_setprio(0);
    __builtin_amdgcn_sched_barrier(0);
    __builtin_amdgcn_s_barrier();
  }

#pragma unroll
  for (int nf = 0; nf < 4; ++nf) {
    int col = n0 + (wn << 6) + (nf << 4) + (lane & 15);
    float bcol = (!BIAS_ROW && bias) ? bias[col] : 0.0f;
#pragma unroll
    for (int mf = 0; mf < 8; ++mf) {
      f32x4 a = acc[mf][nf];
#pragma unroll
      for (int r = 0; r < 4; ++r) {
        int rowg = m0 + (wm << 7) + (mf << 4) + ((lane >> 4) << 2) + r;
        float bv = BIAS_ROW ? (bias ? bias[rowg] : 0.0f) : bcol;
        float v = a[r] * scale + bv;
        if (do_relu) v = fmaxf(v, 0.0f);
        if (OUT_BF16) ((unsigned short*)Cv)[(size_t)rowg * ldc + col] = f2bf(v);
        else          ((float*)Cv)[(size_t)rowg * ldc + col] = v;
      }
    }
  }
}

extern "C" void kernel_launch(void* const* d_in, const int* in_sizes, int n_in,
                              void* d_out, int out_size, void* d_ws, size_t ws_size,
                              hipStream_t stream) {
  const float* X   = (const float*)d_in[0];
  const float* Y   = (const float*)d_in[1];
  const float* R   = (const float*)d_in[2];
  const float* Wi  = (const float*)d_in[3];
  const float* bi  = (const float*)d_in[4];
  const float* Wo  = (const float*)d_in[5];
  const float* bo  = (const float*)d_in[6];
  const float* Wc  = (const float*)d_in[7];
  const float* bc  = (const float*)d_in[8];
  const float* Wf  = (const float*)d_in[9];
  const float* bf_ = (const float*)d_in[10];
  float* out = (float*)d_out;

  char* ws = (char*)d_ws;
  size_t off = 0;
  auto alloc = [&](size_t b) { char* p = ws + off; off += (b + 255) & ~(size_t)255; return p; };
  unsigned short* Xb   = (unsigned short*)alloc((size_t)S_TOK * DIM  * 2);  // later iqk|oqk z=0
  unsigned short* Yb   = (unsigned short*)alloc((size_t)S_TOK * DIM  * 2);  // later iqk|oqk z=1
  unsigned short* Rb   = (unsigned short*)alloc((size_t)S_TOK * DIM  * 2);
  unsigned short* WiT  = (unsigned short*)alloc((size_t)DIM2 * DIM  * 2);
  unsigned short* WoT  = (unsigned short*)alloc((size_t)DIM2 * DIM  * 2);
  unsigned short* WcT  = (unsigned short*)alloc((size_t)DIM2 * DIM2 * 2);
  unsigned short* WfT  = (unsigned short*)alloc((size_t)OUTN * DIM2 * 2);
  unsigned short* iqT  = (unsigned short*)alloc((size_t)DIM2 * S_TOK * 2);  // later meta0/1+MWT0/1
  unsigned short* oqT0 = (unsigned short*)alloc((size_t)DIM2 * S_TOK * 2);  // later icm0
  unsigned short* oqT1 = (unsigned short*)alloc((size_t)DIM2 * S_TOK * 2);  // later icm1
  unsigned short* icmT0= (unsigned short*)alloc((size_t)DIM2 * S_TOK * 2);
  unsigned short* icmT1= (unsigned short*)alloc((size_t)DIM2 * S_TOK * 2);
  unsigned short* iqk0 = Xb;
  unsigned short* oqk0 = Xb + (size_t)DIM2*DIM2;
  unsigned short* iqk1 = Yb;
  unsigned short* oqk1 = Yb + (size_t)DIM2*DIM2;
  unsigned short* meta0= iqT;
  unsigned short* meta1= iqT + (size_t)DIM2*DIM2;
  unsigned short* MWT0 = iqT + (size_t)2*DIM2*DIM2;
  unsigned short* MWT1 = iqT + (size_t)2*DIM2*DIM2 + (size_t)OUTN*DIM2;
  unsigned short* icm0 = oqT0;
  unsigned short* icm1 = oqT1;

  auto cvt = [&](const float* s, unsigned short* d, int n) {
    int n4 = n >> 2;
    cvt_f32_bf16<<<dim3((n4 + 255) / 256), dim3(256), 0, stream>>>(s, d, n4);
  };
  cvt(X, Xb, S_TOK * DIM);
  cvt(Y, Yb, S_TOK * DIM);
  cvt(R, Rb, S_TOK * DIM);
  transpose_to_bf16<1><<<dim3(DIM2 / 64, DIM  / 64), 256, 0, stream>>>(Wi, WiT, DIM,  DIM2);
  transpose_to_bf16<1><<<dim3(DIM2 / 64, DIM  / 64), 256, 0, stream>>>(Wo, WoT, DIM,  DIM2);
  transpose_to_bf16<1><<<dim3(DIM2 / 64, DIM2 / 64), 256, 0, stream>>>(Wc, WcT, DIM2, DIM2);
  transpose_to_bf16<1><<<dim3(OUTN / 64, DIM2 / 64), 256, 0, stream>>>(Wf, WfT, DIM2, OUTN);

  const float rscale = 0.022097086912079608f;  // 1/sqrt(2048)

  // G1: z=3 -> iqT = (X@Wi+bi)^T ; oqT0 = (Y@Wo+bo)^T ; oqT1 = (R@Wo+bo)^T
  {
    GPtr g{};
    g.A[0] = WiT; g.A[1] = WoT; g.A[2] = WoT;
    g.B[0] = Xb;  g.B[1] = Yb;  g.B[2] = Rb;
    g.bias[0] = bi; g.bias[1] = bo; g.bias[2] = bo;
    g.C[0] = iqT; g.C[1] = oqT0; g.C[2] = oqT1;
    gemm256<0,0,1,1><<<dim3(S_TOK/256, DIM2/256, 3), 512, 0, stream>>>(
        g, DIM, DIM, S_TOK, DIM, 1.f, 0);
  }
  // G2: z=2 -> icmT_z = (cat(X, Y|R)@Wc + bc)^T
  {
    GPtr g{};
    g.A[0] = WcT; g.A[1] = WcT;
    g.B[0] = Xb;  g.B[1] = Xb;
    g.Bk2[0] = Yb; g.Bk2[1] = Rb;
    g.bias[0] = bc; g.bias[1] = bc;
    g.C[0] = icmT0; g.C[1] = icmT1;
    gemm256<0,1,1,1><<<dim3(S_TOK/256, DIM2/256, 2), 512, 0, stream>>>(
        g, DIM2, DIM, S_TOK, DIM2, 1.f, 0);
  }
  // SM: column-softmax all 5 activation maps
  {
    SmTab st{};
    st.T[0] = iqT; st.T[1] = oqT0; st.T[2] = oqT1; st.T[3] = icmT0; st.T[4] = icmT1;
    softmax_cols<<<dim3(S_TOK / 64, 5), dim3(512), 0, stream>>>(st);
  }
  // G3: z=2 -> [iqk_z; oqk_z] = [iqT; oqT_z] @ icmT_z^T   (M=4096, K=8192)
  {
    GPtr g{};
    g.A[0] = iqT; g.A[1] = iqT;
    g.Arow2[0] = oqT0; g.Arow2[1] = oqT1;
    g.B[0] = icmT0; g.B[1] = icmT1;
    g.C[0] = iqk0; g.C[1] = iqk1;
    gemm256<1,0,0,1><<<dim3(DIM2/256, 4096/256, 2), 512, 0, stream>>>(
        g, S_TOK, S_TOK, DIM2, S_TOK, 1.f, 0);
  }
  // T: icm_z = transpose(icmT_z)
  transpose_to_bf16<0><<<dim3(S_TOK / 64, DIM2 / 64), 256, 0, stream>>>(icmT0, icm0, DIM2, S_TOK);
  transpose_to_bf16<0><<<dim3(S_TOK / 64, DIM2 / 64), 256, 0, stream>>>(icmT1, icm1, DIM2, S_TOK);
  // G4: z=2 -> meta_z = relu(iqk_z @ oqk_z^T)
  {
    GPtr g{};
    g.A[0] = iqk0; g.A[1] = iqk1;
    g.B[0] = oqk0; g.B[1] = oqk1;
    g.C[0] = meta0; g.C[1] = meta1;
    gemm_nt<0,0,0,1><<<dim3(DIM2/128, DIM2/128, 2), 256, 0, stream>>>(
        g, DIM2, DIM2, DIM2, DIM2, 1.f, 1);
  }
  // G5: z=2 -> MWT_z = (WfT @ meta_z^T) * rscale
  {
    GPtr g{};
    g.A[0] = WfT; g.A[1] = WfT;
    g.B[0] = meta0; g.B[1] = meta1;
    g.C[0] = MWT0; g.C[1] = MWT1;
    gemm_nt<0,0,0,1><<<dim3(DIM2/128, OUTN/128, 2), 256, 0, stream>>>(
        g, DIM2, DIM2, DIM2, DIM2, rscale, 0);
  }
  // G6: z=2 -> out_z = relu(icm_z @ MWT_z^T + bf)   [8192,1024] f32
  {
    GPtr g{};
    g.A[0] = icm0; g.A[1] = icm1;
    g.B[0] = MWT0; g.B[1] = MWT1;
    g.bias[0] = bf_; g.bias[1] = bf_;
    g.C[0] = out; g.C[1] = out + (size_t)S_TOK * OUTN;
    gemm256<0,0,0,0><<<dim3(OUTN/256, S_TOK/256, 2), 512, 0, stream>>>(
        g, DIM2, DIM2, OUTN, DIM2, 1.f, 1);
  }
  (void)in_sizes; (void)n_in; (void)out_size; (void)ws_size;
}